// Round 5
// baseline (155.876 us; speedup 1.0000x reference)
//
#include <hip/hip_runtime.h>

// Problem constants
#define D_K   1024      // hidden dim (GEMM K)
#define ROWS  16384     // B*L
#define MLP   500
#define NEG   0.01f

// GEMM geometry
#define BM    256
#define BN    256
#define BK    32
#define NT    (D_K / BK)        // 32 K-tiles
#define SLOT_B (BM * BK * 2)    // 16384 bytes per tile per matrix
#define NBLK  256               // grid size; 1 block/CU (128KB LDS forces it)

typedef __bf16 bf16x8 __attribute__((ext_vector_type(8)));
typedef float  f32x4  __attribute__((ext_vector_type(4)));

#define GL(p) ((const __attribute__((address_space(1))) void*)(p))
#define LD(p) ((__attribute__((address_space(3))) void*)(p))

__device__ __forceinline__ ushort f2bf(float f) {
    union { float f; unsigned u; } v; v.f = f;
    unsigned u = v.u;
    unsigned r = (u + 0x7FFFu + ((u >> 16) & 1u)) >> 16;   // RNE
    return (ushort)r;
}

// T2 swizzle (r2/r3-verified involution): XOR byte bits 4-5 with bits 7-8.
__device__ __forceinline__ unsigned swz(unsigned x) {
    return x ^ (((x >> 7) & 3u) << 4);
}

// Device-wide sense-reversing barrier. All 256 blocks are co-resident
// (1 block/CU, LDS-bound), so spinning cannot deadlock. AGENT-scope
// acq/rel gives cross-XCD visibility (L2 wb/inv).
__device__ __forceinline__ void gridbar(unsigned* bar, int tid) {
    __syncthreads();
    if (tid == 0) {
        unsigned g = __hip_atomic_load(&bar[1], __ATOMIC_ACQUIRE, __HIP_MEMORY_SCOPE_AGENT);
        unsigned a = __hip_atomic_fetch_add(&bar[0], 1u, __ATOMIC_ACQ_REL, __HIP_MEMORY_SCOPE_AGENT);
        if (a == NBLK - 1) {
            __hip_atomic_store(&bar[0], 0u, __ATOMIC_RELAXED, __HIP_MEMORY_SCOPE_AGENT);
            __hip_atomic_fetch_add(&bar[1], 1u, __ATOMIC_RELEASE, __HIP_MEMORY_SCOPE_AGENT);
        } else {
            while (__hip_atomic_load(&bar[1], __ATOMIC_ACQUIRE, __HIP_MEMORY_SCOPE_AGENT) == g)
                __builtin_amdgcn_s_sleep(2);
        }
    }
    __syncthreads();
}

// ================= fused persistent kernel: prep -> GEMM+epilogue -> bcast =================
__global__ __launch_bounds__(512, 2) void fused_all(const float* __restrict__ hs,
                                                    const float* __restrict__ Wd,
                                                    const float* __restrict__ bd,
                                                    const float* __restrict__ Wh,
                                                    const float* __restrict__ bh,
                                                    const float* __restrict__ Wc,
                                                    const float* __restrict__ bcp,
                                                    ushort* __restrict__ A,
                                                    ushort* __restrict__ Bt,
                                                    float* __restrict__ bias,
                                                    float* __restrict__ wc,
                                                    float* __restrict__ sd,
                                                    float* __restrict__ sh,
                                                    float* __restrict__ out,
                                                    unsigned* __restrict__ bar) {
    __shared__ ushort As[4 * BM * BK];   // 64 KB
    __shared__ ushort Bs[4 * BN * BK];   // 64 KB

    const int tid  = threadIdx.x;
    const int lane = tid & 63;
    const int wave = tid >> 6;            // 0..7
    const int flat = blockIdx.x;          // 0..255

    // XCD-aware bijective swizzle: 32 consecutive sflat per XCD -> the 4
    // bn-blocks sharing an A panel land on one XCD's L2.
    const int sflat = (flat & 7) * 32 + (flat >> 3);
    const int bn = sflat & 3, bm = sflat >> 2;
    const size_t row0 = (size_t)bm * BM;
    const int col0 = bn * BN;

    // ---------------- stage 1: prep ----------------
    {
        // (a) one W 64x64 transpose tile per block (256 jobs == 256 blocks)
        ushort* tb = As;                      // reuse LDS
        const int z = flat >> 7, rem = flat & 127;
        const int kx = rem & 15, ny = rem >> 4;
        const float* W = z ? Wh : Wd;
        const int k0 = kx * 64, n0 = ny * 64;
        const int c = tid & 63;
        for (int r = wave; r < 64; r += 8) {
            int n = n0 + c;
            float v = (n < MLP) ? W[(size_t)(k0 + r) * MLP + n] : 0.f;
            tb[c * 72 + r] = f2bf(v);
        }
        __syncthreads();
        const int nbase = z * 512 + n0;
        for (int rr = wave; rr < 64; rr += 8)
            Bt[(size_t)(nbase + rr) * D_K + k0 + c] = tb[rr * 72 + c];

        // (b) convert this block's OWN A-panel quarter (64 rows x 1024) ->
        //     data lands in the consuming XCD's L2.
        const size_t arow0 = row0 + (size_t)bn * 64;
        const float4* hs4 = (const float4*)hs;
        ushort4* A4 = (ushort4*)A;
#pragma unroll
        for (int it = 0; it < 32; ++it) {
            int idx = it * 512 + tid;            // 64 rows * 256 float4
            int r = idx >> 8, c4 = idx & 255;
            float4 f = hs4[(arow0 + r) * 256 + c4];
            ushort4 o;
            o.x = f2bf(f.x); o.y = f2bf(f.y); o.z = f2bf(f.z); o.w = f2bf(f.w);
            A4[(arow0 + r) * 256 + c4] = o;
        }

        // (c) pad bias + Wc (block 0 only)
        if (flat == 0) {
            for (int n = tid; n < 1024; n += 512) {
                float bv = 0.f, w0 = 0.f, w1 = 0.f;
                if (n < 512) {
                    if (n < MLP) { bv = bd[n]; w0 = Wc[n * 2]; w1 = Wc[n * 2 + 1]; }
                } else {
                    int m = n - 512;
                    if (m < MLP) { bv = bh[m]; w0 = Wc[(MLP + m) * 2]; w1 = Wc[(MLP + m) * 2 + 1]; }
                }
                bias[n] = bv; wc[n * 2] = w0; wc[n * 2 + 1] = w1;
            }
        }
        // (d) zero this bm's score rows (bn==0 -> sd, bn==1 -> sh)
        if (bn == 0 && tid < 128) ((float4*)(sd + row0 * 2))[tid] = make_float4(0.f, 0.f, 0.f, 0.f);
        if (bn == 1 && tid < 128) ((float4*)(sh + row0 * 2))[tid] = make_float4(0.f, 0.f, 0.f, 0.f);
    }

    gridbar(bar, tid);

    // ---------------- stage 2: GEMM (r3 structure, unchanged) ----------------
    const int wm = wave >> 2, wn = wave & 3;
    char* AsB = (char*)As;
    char* BsB = (char*)Bs;

    const ushort* aptr[2]; const ushort* bptr[2];
    unsigned ldst[2];
#pragma unroll
    for (int i = 0; i < 2; ++i) {
        unsigned x = (unsigned)wave * 1024u + (unsigned)i * 8192u + (unsigned)lane * 16u;
        ldst[i] = x;
        unsigned sx = swz(x);
        unsigned row = sx >> 6, cb = sx & 63;
        aptr[i] = A  + (row0 + row) * D_K + (cb >> 1);
        bptr[i] = Bt + (size_t)((unsigned)col0 + row) * D_K + (cb >> 1);
    }

    const unsigned l15 = lane & 15, c16 = (unsigned)(lane >> 4) * 16u;
    unsigned yA[8], yB[4];
#pragma unroll
    for (int m = 0; m < 8; ++m) yA[m] = swz(((unsigned)(wm * 128 + m * 16) + l15) * 64u + c16);
#pragma unroll
    for (int n = 0; n < 4; ++n) yB[n] = swz(((unsigned)(wn * 64 + n * 16) + l15) * 64u + c16);

    f32x4 acc[8][4] = {};

#define STAGE_A(t) { const int sl_ = (t) & 3;                                                             \
    __builtin_amdgcn_global_load_lds(GL(aptr[0] + (t) * BK), LD(AsB + sl_ * SLOT_B + ldst[0]), 16, 0, 0); \
    __builtin_amdgcn_global_load_lds(GL(aptr[1] + (t) * BK), LD(AsB + sl_ * SLOT_B + ldst[1]), 16, 0, 0); }
#define STAGE_B(t) { const int sl_ = (t) & 3;                                                             \
    __builtin_amdgcn_global_load_lds(GL(bptr[0] + (t) * BK), LD(BsB + sl_ * SLOT_B + ldst[0]), 16, 0, 0); \
    __builtin_amdgcn_global_load_lds(GL(bptr[1] + (t) * BK), LD(BsB + sl_ * SLOT_B + ldst[1]), 16, 0, 0); }

    STAGE_A(0); STAGE_B(0);
    STAGE_A(1); STAGE_B(1);
    STAGE_A(2); STAGE_B(2);
    asm volatile("s_waitcnt vmcnt(8)" ::: "memory");
    __builtin_amdgcn_s_barrier();

    for (int t = 0; t < NT; ++t) {
        const int sl = t & 3;
        char* Asl = AsB + sl * SLOT_B;
        char* Bsl = BsB + sl * SLOT_B;

        // phase A: frags(m0-3 x n0-3) + stage A-half(t+3)
        bf16x8 bf[4], af[4];
#pragma unroll
        for (int n = 0; n < 4; ++n) bf[n] = *(const bf16x8*)(Bsl + yB[n]);
#pragma unroll
        for (int m = 0; m < 4; ++m) af[m] = *(const bf16x8*)(Asl + yA[m]);
        if (t + 3 < NT) STAGE_A(t + 3);
        __builtin_amdgcn_s_barrier();
        asm volatile("s_waitcnt lgkmcnt(0)" ::: "memory");
        __builtin_amdgcn_sched_barrier(0);
        __builtin_amdgcn_s_setprio(1);
#pragma unroll
        for (int m = 0; m < 4; ++m)
#pragma unroll
            for (int n = 0; n < 4; ++n)
                acc[m][n] = __builtin_amdgcn_mfma_f32_16x16x32_bf16(af[m], bf[n], acc[m][n], 0, 0, 0);
        __builtin_amdgcn_s_setprio(0);
        __builtin_amdgcn_sched_barrier(0);
        __builtin_amdgcn_s_barrier();

        // phase B: frags(m4-7, reuse bf) + stage B-half(t+3) + counted vmcnt
        bf16x8 ag[4];
#pragma unroll
        for (int m = 0; m < 4; ++m) ag[m] = *(const bf16x8*)(Asl + yA[m + 4]);
        if (t + 3 < NT) STAGE_B(t + 3);
        if (t + 3 < NT)      asm volatile("s_waitcnt vmcnt(8)" ::: "memory");
        else if (t + 2 < NT) asm volatile("s_waitcnt vmcnt(4)" ::: "memory");
        else if (t + 1 < NT) asm volatile("s_waitcnt vmcnt(0)" ::: "memory");
        __builtin_amdgcn_s_barrier();
        asm volatile("s_waitcnt lgkmcnt(0)" ::: "memory");
        __builtin_amdgcn_sched_barrier(0);
        __builtin_amdgcn_s_setprio(1);
#pragma unroll
        for (int m = 0; m < 4; ++m)
#pragma unroll
            for (int n = 0; n < 4; ++n)
                acc[m + 4][n] = __builtin_amdgcn_mfma_f32_16x16x32_bf16(ag[m], bf[n], acc[m + 4][n], 0, 0, 0);
        __builtin_amdgcn_s_setprio(0);
        __builtin_amdgcn_sched_barrier(0);
        __builtin_amdgcn_s_barrier();
    }
#undef STAGE_A
#undef STAGE_B

    // Epilogue: bias + leakyrelu + rank-2 contraction, 16-lane reduce, atomic add.
    {
        float bv[4], w0v[4], w1v[4];
#pragma unroll
        for (int nf = 0; nf < 4; ++nf) {
            int cc = col0 + wn * 64 + nf * 16 + (int)l15;
            bv[nf] = bias[cc]; w0v[nf] = wc[2 * cc]; w1v[nf] = wc[2 * cc + 1];
        }
        float* S = (bn < 2) ? sd : sh;
#pragma unroll
        for (int mf = 0; mf < 8; ++mf) {
            size_t rowb = row0 + (size_t)(wm * 128 + mf * 16 + (lane >> 4) * 4);
#pragma unroll
            for (int r = 0; r < 4; ++r) {
                float s0 = 0.f, s1 = 0.f;
#pragma unroll
                for (int nf = 0; nf < 4; ++nf) {
                    float h = acc[mf][nf][r] + bv[nf];
                    h = (h > 0.f) ? h : NEG * h;
                    s0 += h * w0v[nf]; s1 += h * w1v[nf];
                }
#pragma unroll
                for (int m = 1; m < 16; m <<= 1) {
                    s0 += __shfl_xor(s0, m, 64);
                    s1 += __shfl_xor(s1, m, 64);
                }
                if (l15 == 0) {
                    atomicAdd(&S[(rowb + r) * 2 + 0], s0);
                    atomicAdd(&S[(rowb + r) * 2 + 1], s1);
                }
            }
        }
    }

    gridbar(bar, tid);

    // ---------------- stage 3: broadcast add ----------------
    // out[b,i,j,c] = sd[b,i,c] + sh[b,j,c] + bc[c]; 64 bi-rows per block, 8/wave.
    {
        const float bc0 = bcp[0], bc1 = bcp[1];
        const int bi0 = flat * 64;
#pragma unroll
        for (int k = 0; k < 8; ++k) {
            const int bi = bi0 + wave * 8 + k;
            const int b  = bi >> 10;
            const float v0 = sd[bi * 2 + 0] + bc0;
            const float v1 = sd[bi * 2 + 1] + bc1;
            const f32x4* shrow = (const f32x4*)(sh + (size_t)b * 2048);
            f32x4* orow = (f32x4*)(out + (size_t)bi * 2048);
#pragma unroll
            for (int j = 0; j < 8; ++j) {
                f32x4 s = shrow[lane + j * 64];
                f32x4 o;
                o.x = v0 + s.x; o.y = v1 + s.y; o.z = v0 + s.z; o.w = v1 + s.w;
                __builtin_nontemporal_store(o, &orow[lane + j * 64]);
            }
        }
    }
}

extern "C" void kernel_launch(void* const* d_in, const int* in_sizes, int n_in,
                              void* d_out, int out_size, void* d_ws, size_t ws_size,
                              hipStream_t stream) {
    const float* hs = (const float*)d_in[0];
    const float* Wd = (const float*)d_in[1];
    const float* bd = (const float*)d_in[2];
    const float* Wh = (const float*)d_in[3];
    const float* bh = (const float*)d_in[4];
    const float* Wc = (const float*)d_in[5];
    const float* bc = (const float*)d_in[6];
    float* out = (float*)d_out;

    char* ws = (char*)d_ws;
    ushort*   A    = (ushort*)(ws);                 // 33,554,432 B
    ushort*   Bt   = (ushort*)(ws + 33554432);      //  2,097,152 B
    float*    bias = (float*) (ws + 35651584);      //  4 KB
    float*    wcp  = (float*) (ws + 35655680);      //  8 KB
    float*    sd   = (float*) (ws + 35663872);      //  128 KB
    float*    sh   = (float*) (ws + 35794944);      //  128 KB
    unsigned* bar  = (unsigned*)(ws + 35926016);    //  8 B barrier state

    (void)hipMemsetAsync(bar, 0, 8, stream);        // reset barrier each replay
    fused_all<<<NBLK, 512, 0, stream>>>(hs, Wd, bd, Wh, bh, Wc, bc,
                                        A, Bt, bias, wcp, sd, sh, out, bar);
}

// Round 6
// 88.785 us; speedup vs baseline: 1.7557x; 1.7557x over previous
//
#include <hip/hip_runtime.h>

// Problem constants
#define D_K   1024      // hidden dim (GEMM K)
#define ROWS  16384     // B*L
#define MLP   500
#define NEG   0.01f

// GEMM geometry
#define BM    256
#define BN    256
#define BK    32
#define NT    (D_K / BK)        // 32 K-tiles
#define SLOT_B (BM * BK * 2)    // 16384 bytes per tile per matrix

typedef __bf16 bf16x8 __attribute__((ext_vector_type(8)));
typedef float  f32x4  __attribute__((ext_vector_type(4)));

#define GL(p) ((const __attribute__((address_space(1))) void*)(p))
#define LD(p) ((__attribute__((address_space(3))) void*)(p))

__device__ __forceinline__ ushort f2bf(float f) {
    union { float f; unsigned u; } v; v.f = f;
    unsigned u = v.u;
    unsigned r = (u + 0x7FFFu + ((u >> 16) & 1u)) >> 16;   // RNE
    return (ushort)r;
}

// T2 swizzle (r2/r3-verified involution): XOR byte bits 4-5 with bits 7-8.
__device__ __forceinline__ unsigned swz(unsigned x) {
    return x ^ (((x >> 7) & 3u) << 4);
}

// ---------------- prep-lite: W transpose+pad, bias/Wc pad, zero scores ----------------
__global__ __launch_bounds__(256) void prep_lite(const float* __restrict__ Wd,
                                                 const float* __restrict__ bd,
                                                 const float* __restrict__ Wh,
                                                 const float* __restrict__ bh,
                                                 const float* __restrict__ Wc,
                                                 ushort* __restrict__ Bt,
                                                 float* __restrict__ bias_pad,
                                                 float* __restrict__ wc_pad,
                                                 float4* __restrict__ zero_area) {
    __shared__ ushort tbuf[64][72];
    const int bid = blockIdx.x, tid = threadIdx.x;
    if (bid < 256) {
        // W [1024][500] -> Bt bf16 [1024][1024] transposed + zero-padded
        int b = bid;
        const int z = b >> 7; b &= 127;
        const int kx = b & 15, ny = b >> 4;
        const float* W = z ? Wh : Wd;
        const int k0 = kx * 64, n0 = ny * 64;
        const int c = tid & 63, r4 = tid >> 6;
        for (int r = r4; r < 64; r += 4) {
            int n = n0 + c;
            float v = (n < MLP) ? W[(size_t)(k0 + r) * MLP + n] : 0.f;
            tbuf[c][r] = f2bf(v);
        }
        __syncthreads();
        const int nbase = z * 512 + n0;
        for (int rr = r4; rr < 64; rr += 4)
            Bt[(size_t)(nbase + rr) * D_K + k0 + c] = tbuf[rr][c];
    } else if (bid < 260) {
        // pad bias + Wc
        int n = (bid - 256) * 256 + tid;   // [0,1024)
        float bv = 0.f, w0 = 0.f, w1 = 0.f;
        if (n < 512) {
            if (n < MLP) { bv = bd[n]; w0 = Wc[n * 2]; w1 = Wc[n * 2 + 1]; }
        } else {
            int m = n - 512;
            if (m < MLP) { bv = bh[m]; w0 = Wc[(MLP + m) * 2]; w1 = Wc[(MLP + m) * 2 + 1]; }
        }
        bias_pad[n] = bv; wc_pad[n * 2] = w0; wc_pad[n * 2 + 1] = w1;
    } else {
        // zero sd+sh (256 KB contiguous)
        int i = (bid - 260) * 256 + tid;   // [0,16384) float4
        zero_area[i] = make_float4(0.f, 0.f, 0.f, 0.f);
    }
}

// ---------------- 256x256 GEMM with fused f32->bf16 A-staging ----------------
// A is read DIRECTLY from hs (f32): global->reg->cvt->swizzled ds_write.
// B via global_load_lds from pre-transposed bf16 Bt.
// C[row,n] = A[row,:] . Bt[n,:]; h = leakyrelu(C+bias); scores += h . wc (atomic)
__global__ __launch_bounds__(512, 2) void gemm_scores(const float* __restrict__ hs,
                                                      const ushort* __restrict__ Bt,
                                                      const float* __restrict__ bias,
                                                      const float* __restrict__ wc,
                                                      float* __restrict__ sd,
                                                      float* __restrict__ sh) {
    __shared__ ushort As[4 * BM * BK];   // 64 KB
    __shared__ ushort Bs[4 * BN * BK];   // 64 KB
    const int tid  = threadIdx.x;
    const int lane = tid & 63;
    const int wave = tid >> 6;            // 0..7
    const int wm = wave >> 2, wn = wave & 3;

    // XCD-aware bijective swizzle: 32 consecutive sflat per XCD -> the 4
    // bn-blocks sharing an A panel (and its hs f32 source) on one XCD's L2.
    const int flat  = blockIdx.y * gridDim.x + blockIdx.x;
    const int sflat = (flat & 7) * 32 + (flat >> 3);
    const int bn = sflat & 3, bm = sflat >> 2;
    const size_t row0 = (size_t)bm * BM;
    const int col0 = bn * BN;

    char* AsB = (char*)As;
    char* BsB = (char*)Bs;

    // B staging (gload_lds): linear LDS dest, inverse-swizzled global source.
    const ushort* bptr[2];
    unsigned ldst[2];
#pragma unroll
    for (int i = 0; i < 2; ++i) {
        unsigned x = (unsigned)wave * 1024u + (unsigned)i * 8192u + (unsigned)lane * 16u;
        ldst[i] = x;
        unsigned sx = swz(x);
        unsigned row = sx >> 6, cb = sx & 63;
        bptr[i] = Bt + (size_t)((unsigned)col0 + row) * D_K + (cb >> 1);
    }

    // A reg-staging addressing: thread covers rows arow+j*64 (j=0..3), 16B col ac4.
    const int arow = tid >> 3;           // 0..63
    const int ac4  = tid & 7;            // 0..7 (float4 units within the 32-float k-slice)
    const float4* hsp = (const float4*)hs;
    size_t aoff[4]; unsigned awz[4];
#pragma unroll
    for (int j = 0; j < 4; ++j) {
        aoff[j] = (row0 + (size_t)(arow + j * 64)) * 256 + ac4;
        awz[j]  = swz((unsigned)(arow + j * 64) * 64u + (unsigned)ac4 * 8u);
    }

    // ds_read fragment offsets (swizzled)
    const unsigned l15 = lane & 15, c16 = (unsigned)(lane >> 4) * 16u;
    unsigned yA[8], yB[4];
#pragma unroll
    for (int m = 0; m < 8; ++m) yA[m] = swz(((unsigned)(wm * 128 + m * 16) + l15) * 64u + c16);
#pragma unroll
    for (int n = 0; n < 4; ++n) yB[n] = swz(((unsigned)(wn * 64 + n * 16) + l15) * 64u + c16);

    f32x4 acc[8][4] = {};
    float4 R0[4], R1[4];

#define BSTAGE(t) { const int sl_ = (t) & 3;                                                              \
    __builtin_amdgcn_global_load_lds(GL(bptr[0] + (t) * BK), LD(BsB + sl_ * SLOT_B + ldst[0]), 16, 0, 0); \
    __builtin_amdgcn_global_load_lds(GL(bptr[1] + (t) * BK), LD(BsB + sl_ * SLOT_B + ldst[1]), 16, 0, 0); }
#define ALOAD(R, t) { _Pragma("unroll")                                                                   \
    for (int j = 0; j < 4; ++j) R[j] = hsp[aoff[j] + (t) * 8]; }
#define AWRITE(R, t) { const int sl_ = (t) & 3; _Pragma("unroll")                                         \
    for (int j = 0; j < 4; ++j) {                                                                         \
        float4 f = R[j]; ushort4 o;                                                                       \
        o.x = f2bf(f.x); o.y = f2bf(f.y); o.z = f2bf(f.z); o.w = f2bf(f.w);                               \
        *(ushort4*)(AsB + sl_ * SLOT_B + awz[j]) = o; } }

    // Prologue: B slots 0-2 staged; A slots 0-1 written; tile-2 loads in flight (R0).
    BSTAGE(0); BSTAGE(1); BSTAGE(2);
    ALOAD(R0, 0); ALOAD(R1, 1);
    AWRITE(R0, 0);                 // compiler's counted vmcnt here drains BSTAGE(0..2) too
    AWRITE(R1, 1);
    ALOAD(R0, 2);
    asm volatile("s_waitcnt lgkmcnt(0)" ::: "memory");
    __builtin_amdgcn_s_barrier();

    // TILE(t): phase A {frags, ALOAD(t+3)->Rload, MFMA m0-3}
    //          phase B {frags, AWRITE(t+2) from Rwrite, BSTAGE(t+3), MFMA m4-7}
#define TILE(t, Rload, Rwrite) {                                                          \
    const int sl = (t) & 3;                                                               \
    char* Asl = AsB + sl * SLOT_B;                                                        \
    char* Bsl = BsB + sl * SLOT_B;                                                        \
    bf16x8 bf[4], af[4];                                                                  \
    _Pragma("unroll") for (int n = 0; n < 4; ++n) bf[n] = *(const bf16x8*)(Bsl + yB[n]);  \
    _Pragma("unroll") for (int m = 0; m < 4; ++m) af[m] = *(const bf16x8*)(Asl + yA[m]);  \
    if ((t) + 3 < NT) ALOAD(Rload, (t) + 3);                                              \
    __builtin_amdgcn_s_barrier();                                                         \
    asm volatile("s_waitcnt lgkmcnt(0)" ::: "memory");                                    \
    __builtin_amdgcn_sched_barrier(0);                                                    \
    __builtin_amdgcn_s_setprio(1);                                                        \
    _Pragma("unroll") for (int m = 0; m < 4; ++m)                                         \
        _Pragma("unroll") for (int n = 0; n < 4; ++n)                                     \
            acc[m][n] = __builtin_amdgcn_mfma_f32_16x16x32_bf16(af[m], bf[n], acc[m][n], 0, 0, 0); \
    __builtin_amdgcn_s_setprio(0);                                                        \
    __builtin_amdgcn_sched_barrier(0);                                                    \
    __builtin_amdgcn_s_barrier();                                                         \
    bf16x8 ag[4];                                                                         \
    _Pragma("unroll") for (int m = 0; m < 4; ++m) ag[m] = *(const bf16x8*)(Asl + yA[m + 4]); \
    if ((t) + 2 < NT) AWRITE(Rwrite, (t) + 2);                                            \
    if ((t) + 3 < NT) BSTAGE((t) + 3);                                                    \
    if ((t) + 2 >= NT) asm volatile("s_waitcnt vmcnt(0)" ::: "memory");                   \
    __builtin_amdgcn_s_barrier();                                                         \
    asm volatile("s_waitcnt lgkmcnt(0)" ::: "memory");                                    \
    __builtin_amdgcn_sched_barrier(0);                                                    \
    __builtin_amdgcn_s_setprio(1);                                                        \
    _Pragma("unroll") for (int m = 0; m < 4; ++m)                                         \
        _Pragma("unroll") for (int n = 0; n < 4; ++n)                                     \
            acc[m + 4][n] = __builtin_amdgcn_mfma_f32_16x16x32_bf16(ag[m], bf[n], acc[m + 4][n], 0, 0, 0); \
    __builtin_amdgcn_s_setprio(0);                                                        \
    __builtin_amdgcn_sched_barrier(0);                                                    \
    __builtin_amdgcn_s_barrier(); }

    for (int t = 0; t < NT; t += 2) {
        TILE(t,     R1, R0);   // loads tile t+3 (odd) -> R1; writes tile t+2 (even) from R0
        TILE(t + 1, R0, R1);   // loads tile t+4 (even) -> R0; writes tile t+3 (odd) from R1
    }
#undef TILE
#undef BSTAGE
#undef ALOAD
#undef AWRITE

    // Epilogue: bias + leakyrelu + rank-2 contraction, 16-lane reduce, atomic add.
    // C/D layout: col = lane&15, row = (lane>>4)*4 + reg  [m89-verified]
    float bv[4], w0v[4], w1v[4];
#pragma unroll
    for (int nf = 0; nf < 4; ++nf) {
        int cc = col0 + wn * 64 + nf * 16 + (int)l15;
        bv[nf] = bias[cc]; w0v[nf] = wc[2 * cc]; w1v[nf] = wc[2 * cc + 1];
    }
    float* S = (bn < 2) ? sd : sh;
#pragma unroll
    for (int mf = 0; mf < 8; ++mf) {
        size_t rowb = row0 + (size_t)(wm * 128 + mf * 16 + (lane >> 4) * 4);
#pragma unroll
        for (int r = 0; r < 4; ++r) {
            float s0 = 0.f, s1 = 0.f;
#pragma unroll
            for (int nf = 0; nf < 4; ++nf) {
                float h = acc[mf][nf][r] + bv[nf];
                h = (h > 0.f) ? h : NEG * h;
                s0 += h * w0v[nf]; s1 += h * w1v[nf];
            }
#pragma unroll
            for (int m = 1; m < 16; m <<= 1) {
                s0 += __shfl_xor(s0, m, 64);
                s1 += __shfl_xor(s1, m, 64);
            }
            if (l15 == 0) {
                atomicAdd(&S[(rowb + r) * 2 + 0], s0);
                atomicAdd(&S[(rowb + r) * 2 + 1], s1);
            }
        }
    }
}

// ---------------- broadcast add: out[b,i,j,c] = sd[b,i,c] + sh[b,j,c] + bc[c] ----------------
__global__ __launch_bounds__(256) void bcast(const float* __restrict__ sd,
                                             const float* __restrict__ sh,
                                             const float* __restrict__ bc,
                                             float* __restrict__ out) {
    const int bi = blockIdx.x;            // b*1024 + i
    const int b  = bi >> 10;
    const float v0 = sd[bi * 2 + 0] + bc[0];
    const float v1 = sd[bi * 2 + 1] + bc[1];
    const f32x4* shrow = (const f32x4*)(sh + (size_t)b * 2048);
    f32x4* orow = (f32x4*)(out + (size_t)bi * 2048);
#pragma unroll
    for (int t = threadIdx.x; t < 512; t += 256) {
        f32x4 s = shrow[t];
        f32x4 o;
        o.x = v0 + s.x; o.y = v1 + s.y; o.z = v0 + s.z; o.w = v1 + s.w;
        __builtin_nontemporal_store(o, &orow[t]);
    }
}

extern "C" void kernel_launch(void* const* d_in, const int* in_sizes, int n_in,
                              void* d_out, int out_size, void* d_ws, size_t ws_size,
                              hipStream_t stream) {
    const float* hs = (const float*)d_in[0];
    const float* Wd = (const float*)d_in[1];
    const float* bd = (const float*)d_in[2];
    const float* Wh = (const float*)d_in[3];
    const float* bh = (const float*)d_in[4];
    const float* Wc = (const float*)d_in[5];
    const float* bc = (const float*)d_in[6];
    float* out = (float*)d_out;

    char* ws = (char*)d_ws;
    ushort* Bt   = (ushort*)(ws);                 // 2,097,152 B
    float*  bias = (float*) (ws + 2097152);       // 4 KB
    float*  wcp  = (float*) (ws + 2101248);       // 8 KB
    float*  sd   = (float*) (ws + 2109440);       // 128 KB
    float*  sh   = (float*) (ws + 2240512);       // 128 KB (contiguous after sd)

    prep_lite<<<324, 256, 0, stream>>>(Wd, bd, Wh, bh, Wc, Bt, bias, wcp, (float4*)sd);
    gemm_scores<<<dim3(4, 64), 512, 0, stream>>>(hs, Bt, bias, wcp, sd, sh);
    bcast<<<ROWS, 256, 0, stream>>>(sd, sh, bc, out);
}

// Round 7
// 84.241 us; speedup vs baseline: 1.8504x; 1.0539x over previous
//
#include <hip/hip_runtime.h>

// Problem constants
#define D_K   1024      // hidden dim (GEMM K)
#define ROWS  16384     // B*L
#define MLP   500
#define NEG   0.01f

// GEMM geometry
#define BM    256
#define BN    256
#define BK    32
#define NT    (D_K / BK)        // 32 K-tiles
#define SLOT_B (BM * BK * 2)    // 16384 bytes per tile per matrix

typedef __bf16 bf16x8 __attribute__((ext_vector_type(8)));
typedef __bf16 bf16x4 __attribute__((ext_vector_type(4)));
typedef float  f32x4  __attribute__((ext_vector_type(4)));

#define GL(p) ((const __attribute__((address_space(1))) void*)(p))
#define LD(p) ((__attribute__((address_space(3))) void*)(p))

// f32 -> bf16 RNE via hw cvt (compiler emits v_cvt_pk_bf16_f32; m240: casts beat hand-asm)
__device__ __forceinline__ ushort bfc(float x) {
    __bf16 b = (__bf16)x;
    return __builtin_bit_cast(ushort, b);
}

// T2 swizzle (r2/r3-verified involution): XOR byte bits 4-5 with bits 7-8.
__device__ __forceinline__ unsigned swz(unsigned x) {
    return x ^ (((x >> 7) & 3u) << 4);
}

// ---------------- prep-lite: W transpose+pad, bias/Wc pad, zero scores ----------------
__global__ __launch_bounds__(256) void prep_lite(const float* __restrict__ Wd,
                                                 const float* __restrict__ bd,
                                                 const float* __restrict__ Wh,
                                                 const float* __restrict__ bh,
                                                 const float* __restrict__ Wc,
                                                 ushort* __restrict__ Bt,
                                                 float* __restrict__ bias_pad,
                                                 float* __restrict__ wc_pad,
                                                 float4* __restrict__ zero_area) {
    __shared__ ushort tbuf[64][72];
    const int bid = blockIdx.x, tid = threadIdx.x;
    if (bid < 256) {
        // W [1024][500] -> Bt bf16 [1024][1024] transposed + zero-padded
        int b = bid;
        const int z = b >> 7; b &= 127;
        const int kx = b & 15, ny = b >> 4;
        const float* W = z ? Wh : Wd;
        const int k0 = kx * 64, n0 = ny * 64;
        const int c = tid & 63, r4 = tid >> 6;
        for (int r = r4; r < 64; r += 4) {
            int n = n0 + c;
            float v = (n < MLP) ? W[(size_t)(k0 + r) * MLP + n] : 0.f;
            tbuf[c][r] = bfc(v);
        }
        __syncthreads();
        const int nbase = z * 512 + n0;
        for (int rr = r4; rr < 64; rr += 4)
            Bt[(size_t)(nbase + rr) * D_K + k0 + c] = tbuf[rr][c];
    } else if (bid < 260) {
        // pad bias + Wc
        int n = (bid - 256) * 256 + tid;   // [0,1024)
        float bv = 0.f, w0 = 0.f, w1 = 0.f;
        if (n < 512) {
            if (n < MLP) { bv = bd[n]; w0 = Wc[n * 2]; w1 = Wc[n * 2 + 1]; }
        } else {
            int m = n - 512;
            if (m < MLP) { bv = bh[m]; w0 = Wc[(MLP + m) * 2]; w1 = Wc[(MLP + m) * 2 + 1]; }
        }
        bias_pad[n] = bv; wc_pad[n * 2] = w0; wc_pad[n * 2 + 1] = w1;
    } else {
        // zero sd+sh (256 KB contiguous)
        int i = (bid - 260) * 256 + tid;   // [0,16384) float4
        zero_area[i] = make_float4(0.f, 0.f, 0.f, 0.f);
    }
}

// ---------------- 256x256 GEMM, fused f32->bf16 A-staging, 2 barriers/tile ----------------
// A read DIRECTLY from hs (f32): global->reg->cvt->swizzled ds_write (2-tile reg pingpong).
// B via global_load_lds from pre-transposed bf16 Bt.
// Hazard ledger (ring-4, ALOAD t+3, AWRITE t+2, BSTAGE t+3, 1 barrier/phase):
//  - RAW slot t (B): BSTAGE(t) retired by AWRITE(t+1)'s implicit vmcnt at t-1B (pre-bar);
//    cross-wave via phase-A barrier. Tail: explicit vmcnt(0) at t>=NT-2 covers BSTAGE(NT-1).
//  - RAW slot t (A): AWRITE(t) ds_writes at t-2B forced by that wave's lgkm0 (pre t-1A bar).
//  - WAR: writes to slot s at tile t target readers at tile t-2 (A) / t-1 (B), whose reads
//    retired at their lgkm0, >=2 barriers before the write issues. Max wave skew = 1 phase.
__global__ __launch_bounds__(512, 2) void gemm_scores(const float* __restrict__ hs,
                                                      const ushort* __restrict__ Bt,
                                                      const float* __restrict__ bias,
                                                      const float* __restrict__ wc,
                                                      float* __restrict__ sd,
                                                      float* __restrict__ sh) {
    __shared__ ushort As[4 * BM * BK];   // 64 KB
    __shared__ ushort Bs[4 * BN * BK];   // 64 KB
    const int tid  = threadIdx.x;
    const int lane = tid & 63;
    const int wave = tid >> 6;            // 0..7
    const int wm = wave >> 2, wn = wave & 3;

    // XCD-aware bijective swizzle: 32 consecutive sflat per XCD -> the 4
    // bn-blocks sharing an A panel (and its hs f32 source) on one XCD's L2.
    const int flat  = blockIdx.y * gridDim.x + blockIdx.x;
    const int sflat = (flat & 7) * 32 + (flat >> 3);
    const int bn = sflat & 3, bm = sflat >> 2;
    const size_t row0 = (size_t)bm * BM;
    const int col0 = bn * BN;

    char* AsB = (char*)As;
    char* BsB = (char*)Bs;

    // B staging (gload_lds): linear LDS dest, inverse-swizzled global source.
    const ushort* bptr[2];
    unsigned ldst[2];
#pragma unroll
    for (int i = 0; i < 2; ++i) {
        unsigned x = (unsigned)wave * 1024u + (unsigned)i * 8192u + (unsigned)lane * 16u;
        ldst[i] = x;
        unsigned sx = swz(x);
        unsigned row = sx >> 6, cb = sx & 63;
        bptr[i] = Bt + (size_t)((unsigned)col0 + row) * D_K + (cb >> 1);
    }

    // A reg-staging addressing: thread covers rows arow+j*64 (j=0..3), 16B col ac4.
    const int arow = tid >> 3;           // 0..63
    const int ac4  = tid & 7;            // 0..7 (float4 units within the 32-float k-slice)
    const f32x4* hsp = (const f32x4*)hs;
    size_t aoff[4]; unsigned awz[4];
#pragma unroll
    for (int j = 0; j < 4; ++j) {
        aoff[j] = (row0 + (size_t)(arow + j * 64)) * 256 + ac4;
        awz[j]  = swz((unsigned)(arow + j * 64) * 64u + (unsigned)ac4 * 8u);
    }

    // ds_read fragment offsets (swizzled)
    const unsigned l15 = lane & 15, c16 = (unsigned)(lane >> 4) * 16u;
    unsigned yA[8], yB[4];
#pragma unroll
    for (int m = 0; m < 8; ++m) yA[m] = swz(((unsigned)(wm * 128 + m * 16) + l15) * 64u + c16);
#pragma unroll
    for (int n = 0; n < 4; ++n) yB[n] = swz(((unsigned)(wn * 64 + n * 16) + l15) * 64u + c16);

    f32x4 acc[8][4] = {};
    f32x4 R0[4], R1[4];

#define BSTAGE(t) { const int sl_ = (t) & 3;                                                              \
    __builtin_amdgcn_global_load_lds(GL(bptr[0] + (t) * BK), LD(BsB + sl_ * SLOT_B + ldst[0]), 16, 0, 0); \
    __builtin_amdgcn_global_load_lds(GL(bptr[1] + (t) * BK), LD(BsB + sl_ * SLOT_B + ldst[1]), 16, 0, 0); }
#define ALOAD(R, t) { _Pragma("unroll")                                                                   \
    for (int j = 0; j < 4; ++j) R[j] = hsp[aoff[j] + (t) * 8]; }
#define AWRITE(R, t) { const int sl_ = (t) & 3; _Pragma("unroll")                                         \
    for (int j = 0; j < 4; ++j) {                                                                         \
        bf16x4 b = __builtin_convertvector(R[j], bf16x4);                                                 \
        *(bf16x4*)(AsB + sl_ * SLOT_B + awz[j]) = b; } }

    // Prologue: B slots 0-2 staged; A slots 0-1 written; tile-2 loads in flight (R0).
    BSTAGE(0); BSTAGE(1); BSTAGE(2);
    ALOAD(R0, 0); ALOAD(R1, 1);
    AWRITE(R0, 0);
    AWRITE(R1, 1);
    ALOAD(R0, 2);
    asm volatile("s_waitcnt lgkmcnt(0)" ::: "memory");
    __builtin_amdgcn_s_barrier();

    // TILE(t): phase A {frags m0-3+B, ALOAD(t+3), bar, MFMA m0-3}
    //          phase B {frags m4-7,  AWRITE(t+2), BSTAGE(t+3), bar, MFMA m4-7}
#define TILE(t, Rload, Rwrite) {                                                          \
    const int sl = (t) & 3;                                                               \
    char* Asl = AsB + sl * SLOT_B;                                                        \
    char* Bsl = BsB + sl * SLOT_B;                                                        \
    bf16x8 bf[4], af[4];                                                                  \
    _Pragma("unroll") for (int n = 0; n < 4; ++n) bf[n] = *(const bf16x8*)(Bsl + yB[n]);  \
    _Pragma("unroll") for (int m = 0; m < 4; ++m) af[m] = *(const bf16x8*)(Asl + yA[m]);  \
    if ((t) + 3 < NT) ALOAD(Rload, (t) + 3);                                              \
    if ((t) + 2 >= NT) asm volatile("s_waitcnt vmcnt(0)" ::: "memory");                   \
    __builtin_amdgcn_s_barrier();                                                         \
    asm volatile("s_waitcnt lgkmcnt(0)" ::: "memory");                                    \
    __builtin_amdgcn_sched_barrier(0);                                                    \
    __builtin_amdgcn_s_setprio(1);                                                        \
    _Pragma("unroll") for (int m = 0; m < 4; ++m)                                         \
        _Pragma("unroll") for (int n = 0; n < 4; ++n)                                     \
            acc[m][n] = __builtin_amdgcn_mfma_f32_16x16x32_bf16(af[m], bf[n], acc[m][n], 0, 0, 0); \
    __builtin_amdgcn_s_setprio(0);                                                        \
    __builtin_amdgcn_sched_barrier(0);                                                    \
    bf16x8 ag[4];                                                                         \
    _Pragma("unroll") for (int m = 0; m < 4; ++m) ag[m] = *(const bf16x8*)(Asl + yA[m + 4]); \
    if ((t) + 2 < NT) AWRITE(Rwrite, (t) + 2);                                            \
    if ((t) + 3 < NT) BSTAGE((t) + 3);                                                    \
    __builtin_amdgcn_s_barrier();                                                         \
    asm volatile("s_waitcnt lgkmcnt(0)" ::: "memory");                                    \
    __builtin_amdgcn_sched_barrier(0);                                                    \
    __builtin_amdgcn_s_setprio(1);                                                        \
    _Pragma("unroll") for (int m = 0; m < 4; ++m)                                         \
        _Pragma("unroll") for (int n = 0; n < 4; ++n)                                     \
            acc[m + 4][n] = __builtin_amdgcn_mfma_f32_16x16x32_bf16(ag[m], bf[n], acc[m + 4][n], 0, 0, 0); \
    __builtin_amdgcn_s_setprio(0);                                                        \
    __builtin_amdgcn_sched_barrier(0); }

    for (int t = 0; t < NT; t += 2) {
        TILE(t,     R1, R0);   // loads tile t+3 (odd) -> R1; writes tile t+2 (even) from R0
        TILE(t + 1, R0, R1);   // loads tile t+4 (even) -> R0; writes tile t+3 (odd) from R1
    }
#undef TILE
#undef BSTAGE
#undef ALOAD
#undef AWRITE

    // Epilogue: bias + leakyrelu + rank-2 contraction, 16-lane reduce, atomic add.
    // C/D layout: col = lane&15, row = (lane>>4)*4 + reg  [m89-verified]
    float bv[4], w0v[4], w1v[4];
#pragma unroll
    for (int nf = 0; nf < 4; ++nf) {
        int cc = col0 + wn * 64 + nf * 16 + (int)l15;
        bv[nf] = bias[cc]; w0v[nf] = wc[2 * cc]; w1v[nf] = wc[2 * cc + 1];
    }
    float* S = (bn < 2) ? sd : sh;
#pragma unroll
    for (int mf = 0; mf < 8; ++mf) {
        size_t rowb = row0 + (size_t)(wm * 128 + mf * 16 + (lane >> 4) * 4);
#pragma unroll
        for (int r = 0; r < 4; ++r) {
            float s0 = 0.f, s1 = 0.f;
#pragma unroll
            for (int nf = 0; nf < 4; ++nf) {
                float h = acc[mf][nf][r] + bv[nf];
                h = (h > 0.f) ? h : NEG * h;
                s0 += h * w0v[nf]; s1 += h * w1v[nf];
            }
#pragma unroll
            for (int m = 1; m < 16; m <<= 1) {
                s0 += __shfl_xor(s0, m, 64);
                s1 += __shfl_xor(s1, m, 64);
            }
            if (l15 == 0) {
                atomicAdd(&S[(rowb + r) * 2 + 0], s0);
                atomicAdd(&S[(rowb + r) * 2 + 1], s1);
            }
        }
    }
}

// ---------------- broadcast add: out[b,i,j,c] = sd[b,i,c] + sh[b,j,c] + bc[c] ----------------
__global__ __launch_bounds__(256) void bcast(const float* __restrict__ sd,
                                             const float* __restrict__ sh,
                                             const float* __restrict__ bc,
                                             float* __restrict__ out) {
    const int bi = blockIdx.x;            // b*1024 + i
    const int b  = bi >> 10;
    const float v0 = sd[bi * 2 + 0] + bc[0];
    const float v1 = sd[bi * 2 + 1] + bc[1];
    const f32x4* shrow = (const f32x4*)(sh + (size_t)b * 2048);
    f32x4* orow = (f32x4*)(out + (size_t)bi * 2048);
#pragma unroll
    for (int t = threadIdx.x; t < 512; t += 256) {
        f32x4 s = shrow[t];
        f32x4 o;
        o.x = v0 + s.x; o.y = v1 + s.y; o.z = v0 + s.z; o.w = v1 + s.w;
        __builtin_nontemporal_store(o, &orow[t]);
    }
}

extern "C" void kernel_launch(void* const* d_in, const int* in_sizes, int n_in,
                              void* d_out, int out_size, void* d_ws, size_t ws_size,
                              hipStream_t stream) {
    const float* hs = (const float*)d_in[0];
    const float* Wd = (const float*)d_in[1];
    const float* bd = (const float*)d_in[2];
    const float* Wh = (const float*)d_in[3];
    const float* bh = (const float*)d_in[4];
    const float* Wc = (const float*)d_in[5];
    const float* bc = (const float*)d_in[6];
    float* out = (float*)d_out;

    char* ws = (char*)d_ws;
    ushort* Bt   = (ushort*)(ws);                 // 2,097,152 B
    float*  bias = (float*) (ws + 2097152);       // 4 KB
    float*  wcp  = (float*) (ws + 2101248);       // 8 KB
    float*  sd   = (float*) (ws + 2109440);       // 128 KB
    float*  sh   = (float*) (ws + 2240512);       // 128 KB (contiguous after sd)

    prep_lite<<<324, 256, 0, stream>>>(Wd, bd, Wh, bh, Wc, Bt, bias, wcp, (float4*)sd);
    gemm_scores<<<dim3(4, 64), 512, 0, stream>>>(hs, Bt, bias, wcp, sd, sh);
    bcast<<<ROWS, 256, 0, stream>>>(sd, sh, bc, out);
}